// Round 11
// baseline (1493.244 us; speedup 1.0000x reference)
//
#include <hip/hip_runtime.h>
#include <hip/hip_bf16.h>

typedef __bf16 v8bf __attribute__((ext_vector_type(8)));
typedef float  f32x4 __attribute__((ext_vector_type(4)));
typedef unsigned short us8 __attribute__((ext_vector_type(8)));

#define KVOL 27
#define NBKT 16384   // sort buckets
#define SCB  2048    // scan block elements
#define GR   128     // output rows per gather block

__device__ __forceinline__ unsigned short f2bf(float f) {
    unsigned int u = __float_as_uint(f);
    u = u + 0x7FFFu + ((u >> 16) & 1u);   // round-to-nearest-even
    return (unsigned short)(u >> 16);
}
__device__ __forceinline__ float bf2f(unsigned short u) {
    return __uint_as_float((unsigned int)u << 16);
}

// ---------------------------------------------------------------------------
// Prep: W -> bf16 MFMA fragments; zero stats[128].
// ---------------------------------------------------------------------------
__global__ __launch_bounds__(256) void prep_kernel(const float* __restrict__ W,
                                                   unsigned short* __restrict__ wfrag,
                                                   float* __restrict__ stats) {
    if (blockIdx.x == 0 && threadIdx.x < 128) stats[threadIdx.x] = 0.0f;
    int d = blockIdx.x * 256 + threadIdx.x;
    if (d < KVOL * 64 * 64) {
        int i    = d & 7;
        int lane = (d >> 3) & 63;
        int s    = (d >> 9) & 1;
        int t    = (d >> 10) & 3;
        int k    = d >> 12;
        int kin  = s * 32 + (lane >> 4) * 8 + i;
        int c    = t * 16 + (lane & 15);
        wfrag[d] = f2bf(W[k * 4096 + kin * 64 + c]);
    }
}

// Histogram of points by center-tap output row (output-order proxy).
__global__ __launch_bounds__(256) void hist_kernel(const int* __restrict__ oidx,
                                                   int* __restrict__ hist,
                                                   int Npts, int Nout) {
    for (int p = blockIdx.x * 256 + threadIdx.x; p < Npts; p += gridDim.x * 256) {
        int o = oidx[p * KVOL + 13];
        int b = (int)(((long long)o * NBKT) / Nout);
        atomicAdd(&hist[b], 1);
    }
}

__global__ __launch_bounds__(256) void scan_hist(int* __restrict__ hist) {
    __shared__ int ts[256];
    const int tid  = threadIdx.x;
    const int base = tid * 64;
    int s = 0;
    for (int i = 0; i < 64; ++i) s += hist[base + i];
    ts[tid] = s;
    __syncthreads();
    if (tid == 0) {
        int run = 0;
        for (int i = 0; i < 256; ++i) { int v = ts[i]; ts[i] = run; run += v; }
    }
    __syncthreads();
    int run = ts[tid];
    for (int i = 0; i < 64; ++i) { int v = hist[base + i]; hist[base + i] = run; run += v; }
}

__global__ __launch_bounds__(256) void perm_fill(const int* __restrict__ oidx,
                                                 int* __restrict__ cursor,
                                                 int* __restrict__ perm,
                                                 int Npts, int Nout) {
    for (int p = blockIdx.x * 256 + threadIdx.x; p < Npts; p += gridDim.x * 256) {
        int o = oidx[p * KVOL + 13];
        int b = (int)(((long long)o * NBKT) / Nout);
        int pos = atomicAdd(&cursor[b], 1);
        perm[pos] = p;
    }
}

__global__ __launch_bounds__(256) void count_kernel(const int* __restrict__ oidx,
                                                    int* __restrict__ cnt, int M) {
    for (int e = blockIdx.x * 256 + threadIdx.x; e < M; e += gridDim.x * 256)
        atomicAdd(&cnt[oidx[e]], 1);
}

// ------------------------- CSR scan (3 phases) -----------------------------
__global__ __launch_bounds__(256) void scan_part(const int* __restrict__ cnt,
                                                 int* __restrict__ psums, int Nout) {
    __shared__ int ts[256];
    const int b = blockIdx.x, t = threadIdx.x;
    int s = 0;
    int base = b * SCB + t * 8;
    #pragma unroll
    for (int i = 0; i < 8; ++i) { int idx = base + i; s += (idx < Nout) ? cnt[idx] : 0; }
    ts[t] = s;
    __syncthreads();
    if (t == 0) { int r = 0; for (int i = 0; i < 256; ++i) r += ts[i]; psums[b] = r; }
}

__global__ __launch_bounds__(256) void scan_psums(int* __restrict__ psums, int nb) {
    __shared__ int ts[256];
    const int t = threadIdx.x;
    const int chunk = (nb + 255) / 256;
    const int b0 = t * chunk;
    int s = 0;
    for (int i = 0; i < chunk; ++i) { int idx = b0 + i; if (idx < nb) s += psums[idx]; }
    ts[t] = s;
    __syncthreads();
    if (t == 0) { int r = 0; for (int i = 0; i < 256; ++i) { int v = ts[i]; ts[i] = r; r += v; } }
    __syncthreads();
    int run = ts[t];
    for (int i = 0; i < chunk; ++i) {
        int idx = b0 + i;
        if (idx < nb) { int v = psums[idx]; psums[idx] = run; run += v; }
    }
}

__global__ __launch_bounds__(256) void scan_write(const int* __restrict__ cnt,
                                                  const int* __restrict__ psums,
                                                  int* __restrict__ rowptr,
                                                  int* __restrict__ cursor, int Nout) {
    __shared__ int ts[256];
    const int b = blockIdx.x, t = threadIdx.x;
    const int base = b * SCB + t * 8;
    int c[8]; int s = 0;
    #pragma unroll
    for (int i = 0; i < 8; ++i) { int idx = base + i; c[i] = (idx < Nout) ? cnt[idx] : 0; s += c[i]; }
    ts[t] = s;
    __syncthreads();
    if (t == 0) { int r = 0; for (int i = 0; i < 256; ++i) { int v = ts[i]; ts[i] = r; r += v; } }
    __syncthreads();
    int run = psums[b] + ts[t];
    #pragma unroll
    for (int i = 0; i < 8; ++i) {
        int idx = base + i;
        if (idx < Nout) { rowptr[idx] = run; cursor[idx] = run; run += c[i]; }
    }
}

// ent[pos] = p*32 + k  (p = ORIGINAL point id). Perm order for write locality.
__global__ __launch_bounds__(256) void fill_ent(const int* __restrict__ oidx,
                                                const int* __restrict__ perm,
                                                int* __restrict__ cursor,
                                                int* __restrict__ ent, int Npts) {
    for (int pp = blockIdx.x * 256 + threadIdx.x; pp < Npts; pp += gridDim.x * 256) {
        int p = perm[pp];
        #pragma unroll
        for (int k = 0; k < KVOL; ++k) {
            int o = oidx[p * KVOL + k];
            int pos = atomicAdd(&cursor[o], 1);
            ent[pos] = p * 32 + k;
        }
    }
}

// ---------------------------------------------------------------------------
// feat_stats: colsum[64] and S = feats^T feats (bf16 MFMA, fp32 accum).
// ---------------------------------------------------------------------------
__global__ __launch_bounds__(256) void feat_stats(const float* __restrict__ feats,
                                                  float* __restrict__ colsum,
                                                  float* __restrict__ S,
                                                  int Npts) {
    __shared__ unsigned short As[128 * 64];
    const int tid = threadIdx.x;
    const int w = tid >> 6, l = tid & 63, cl = l & 15, hi = l >> 4;
    const int c = tid & 63, rg = tid >> 6;
    const __bf16* Ab = reinterpret_cast<const __bf16*>(As);

    f32x4 acc[4][4];
    #pragma unroll
    for (int a = 0; a < 4; ++a)
        #pragma unroll
        for (int b = 0; b < 4; ++b) acc[a][b] = (f32x4){0.f, 0.f, 0.f, 0.f};
    float csum = 0.f;

    for (int base = blockIdx.x * 128; base < Npts; base += gridDim.x * 128) {
        __syncthreads();
        #pragma unroll
        for (int e = 0; e < 8; ++e) {
            int lin4 = e * 256 + tid;
            int row = lin4 >> 4, col = (lin4 & 15) * 4;
            float4 v = make_float4(0.f, 0.f, 0.f, 0.f);
            if (base + row < Npts)
                v = *reinterpret_cast<const float4*>(feats + (size_t)(base + row) * 64 + col);
            int o = row * 64 + col;
            As[o + 0] = f2bf(v.x); As[o + 1] = f2bf(v.y);
            As[o + 2] = f2bf(v.z); As[o + 3] = f2bf(v.w);
        }
        __syncthreads();
        for (int r = 0; r < 32; ++r) csum += bf2f(As[(rg * 32 + r) * 64 + c]);
        v8bf f[4];
        #pragma unroll
        for (int t = 0; t < 4; ++t)
            #pragma unroll
            for (int i = 0; i < 8; ++i)
                f[t][i] = Ab[(w * 32 + hi * 8 + i) * 64 + cl + 16 * t];
        #pragma unroll
        for (int a = 0; a < 4; ++a)
            #pragma unroll
            for (int b = 0; b < 4; ++b)
                acc[a][b] = __builtin_amdgcn_mfma_f32_16x16x32_bf16(f[a], f[b], acc[a][b], 0, 0, 0);
    }

    unsafeAtomicAdd(&colsum[c], csum);
    #pragma unroll
    for (int a = 0; a < 4; ++a)
        #pragma unroll
        for (int b = 0; b < 4; ++b)
            #pragma unroll
            for (int r = 0; r < 4; ++r) {
                int i = a * 16 + hi * 4 + r;
                int j = b * 16 + cl;
                unsafeAtomicAdd(&S[i * 64 + j], acc[a][b][r]);
            }
}

// qall_mean: per tap k, channel c: q_all += w^T S w ; sum += colsum . w
__global__ __launch_bounds__(64) void qall_mean(const float* __restrict__ W,
                                                const float* __restrict__ colsum,
                                                const float* __restrict__ S,
                                                float* __restrict__ stats) {
    __shared__ float Sl[4096];
    __shared__ float Wl[4096];
    __shared__ float cs[64];
    const int tid = threadIdx.x;
    const int k = blockIdx.x;
    for (int lin = tid; lin < 4096; lin += 64) {
        Sl[lin] = S[lin];
        Wl[lin] = W[k * 4096 + lin];
    }
    cs[tid] = colsum[tid];
    __syncthreads();
    const int c = tid;
    float q = 0.f, sm = 0.f;
    for (int i = 0; i < 64; ++i) {
        float wi = Wl[i * 64 + c];
        sm += cs[i] * wi;
        float d = 0.f;
        #pragma unroll 8
        for (int j = 0; j < 64; ++j) d += Sl[i * 64 + j] * Wl[j * 64 + c];
        q += wi * d;
    }
    unsafeAtomicAdd(&stats[64 + c], q);
    unsafeAtomicAdd(&stats[c], sm);
}

// ---------------------------------------------------------------------------
// gather_conv_bn: block = 128 output rows. Bin CSR entries by tap, MFMA
// 16-entry tiles (feats gathered straight to registers, bf16), accumulate
// into padded LDS accumulator via LDS atomics, then BN+LeakyReLU and ONE
// sequential fp32 store per row. No scattered HBM writes anywhere.
// ---------------------------------------------------------------------------
__global__ __launch_bounds__(256) void gather_conv_bn(const float* __restrict__ feats,
                                                      const unsigned short* __restrict__ wfrag,
                                                      const int* __restrict__ rowptr,
                                                      const int* __restrict__ ent,
                                                      const float* __restrict__ stats,
                                                      const float* __restrict__ gamma,
                                                      const float* __restrict__ beta,
                                                      float* __restrict__ out,
                                                      int Nout, int M) {
    __shared__ float accum[GR * 65];   // stride 65: bank-rotates LDS atomics
    __shared__ int rp[GR + 1];
    __shared__ int blist[2048];
    __shared__ int binoff[32];
    __shared__ int bincur[32];

    const int tid = threadIdx.x;
    const long r0 = (long)blockIdx.x * GR;
    const long nrl = (long)Nout - r0;
    const int nr = nrl > GR ? GR : (int)nrl;

    // BN coefficients for this thread's 32 channels (epilogue layout).
    const int br = tid >> 1, bh = tid & 1;
    const float inv = 1.0f / (float)Nout;
    f32x4 sc[8], sh[8];
    #pragma unroll
    for (int t = 0; t < 8; ++t) {
        int c0 = bh * 32 + t * 4;
        f32x4 m4 = *reinterpret_cast<const f32x4*>(stats + c0);
        f32x4 v4 = *reinterpret_cast<const f32x4*>(stats + 64 + c0);
        f32x4 g4 = *reinterpret_cast<const f32x4*>(gamma + c0);
        f32x4 b4 = *reinterpret_cast<const f32x4*>(beta + c0);
        #pragma unroll
        for (int j = 0; j < 4; ++j) {
            float m   = m4[j] * inv;
            float var = v4[j] * inv - m * m;
            float s   = g4[j] * rsqrtf(var + 1e-5f);
            sc[t][j] = s;
            sh[t][j] = b4[j] - s * m;
        }
    }

    for (int i = tid; i <= GR; i += 256)
        rp[i] = (r0 + i < Nout) ? rowptr[r0 + i] : M;
    for (int i = tid; i < GR * 65; i += 256) accum[i] = 0.f;
    if (tid < 32) { binoff[tid] = 0; bincur[tid] = 0; }
    __syncthreads();

    const int e0 = rp[0];
    const int ne = rp[nr] - e0;

    for (int e = tid; e < ne; e += 256)
        atomicAdd(&bincur[ent[e0 + e] & 31], 1);
    __syncthreads();
    if (tid == 0) {
        int run = 0;
        for (int k = 0; k < KVOL; ++k) { binoff[k] = run; run += bincur[k]; }
        binoff[KVOL] = run;
    }
    __syncthreads();
    if (tid < 32) bincur[tid] = 0;
    __syncthreads();
    for (int e = tid; e < ne; e += 256) {
        int v = ent[e0 + e];
        int k = v & 31, p = v >> 5;
        int lo = 0, hi2 = nr;
        while (hi2 - lo > 1) { int mid = (lo + hi2) >> 1; if (rp[mid] <= e0 + e) lo = mid; else hi2 = mid; }
        int pos = binoff[k] + atomicAdd(&bincur[k], 1);
        blist[pos] = p * 128 + lo;
    }
    __syncthreads();

    const int w = tid >> 6, l = tid & 63, cl = l & 15, hi = l >> 4;
    const v8bf* wfv = reinterpret_cast<const v8bf*>(wfrag);

    for (int k = w; k < KVOL; k += 4) {
        const int bs = binoff[k];
        const int bn = binoff[k + 1] - bs;
        if (bn == 0) continue;
        v8bf b0[4], b1[4];
        #pragma unroll
        for (int t = 0; t < 4; ++t) {
            b0[t] = wfv[((k * 4 + t) * 2 + 0) * 64 + l];
            b1[t] = wfv[((k * 4 + t) * 2 + 1) * 64 + l];
        }
        for (int t0 = 0; t0 < bn; t0 += 16) {
            int idx = t0 + cl;
            us8 u0 = (us8){0, 0, 0, 0, 0, 0, 0, 0};
            us8 u1 = (us8){0, 0, 0, 0, 0, 0, 0, 0};
            int lrow = 0;
            const bool act = idx < bn;
            if (act) {
                int bv = blist[bs + idx];
                lrow = bv & 127;
                const float* src = feats + (size_t)(bv >> 7) * 64 + hi * 8;
                float4 x0 = *reinterpret_cast<const float4*>(src);
                float4 x1 = *reinterpret_cast<const float4*>(src + 4);
                float4 y0 = *reinterpret_cast<const float4*>(src + 32);
                float4 y1 = *reinterpret_cast<const float4*>(src + 36);
                u0[0] = f2bf(x0.x); u0[1] = f2bf(x0.y); u0[2] = f2bf(x0.z); u0[3] = f2bf(x0.w);
                u0[4] = f2bf(x1.x); u0[5] = f2bf(x1.y); u0[6] = f2bf(x1.z); u0[7] = f2bf(x1.w);
                u1[0] = f2bf(y0.x); u1[1] = f2bf(y0.y); u1[2] = f2bf(y0.z); u1[3] = f2bf(y0.w);
                u1[4] = f2bf(y1.x); u1[5] = f2bf(y1.y); u1[6] = f2bf(y1.z); u1[7] = f2bf(y1.w);
            }
            v8bf a0 = *reinterpret_cast<v8bf*>(&u0);
            v8bf a1 = *reinterpret_cast<v8bf*>(&u1);
            f32x4 acc[4];
            #pragma unroll
            for (int t = 0; t < 4; ++t) {
                acc[t] = (f32x4){0.f, 0.f, 0.f, 0.f};
                acc[t] = __builtin_amdgcn_mfma_f32_16x16x32_bf16(b0[t], a0, acc[t], 0, 0, 0);
                acc[t] = __builtin_amdgcn_mfma_f32_16x16x32_bf16(b1[t], a1, acc[t], 0, 0, 0);
            }
            if (act) {
                float* arow = &accum[lrow * 65 + hi * 4];
                #pragma unroll
                for (int t = 0; t < 4; ++t)
                    #pragma unroll
                    for (int j = 0; j < 4; ++j)
                        atomicAdd(&arow[t * 16 + j], acc[t][j]);
            }
        }
    }
    __syncthreads();

    if (br < nr) {
        const float* arow = &accum[br * 65 + bh * 32];
        float* dst = out + (size_t)(r0 + br) * 64 + bh * 32;
        #pragma unroll
        for (int t = 0; t < 8; ++t) {
            f32x4 v;
            #pragma unroll
            for (int j = 0; j < 4; ++j) v[j] = arow[t * 4 + j];
            f32x4 y = v * sc[t] + sh[t];
            #pragma unroll
            for (int j = 0; j < 4; ++j) y[j] = y[j] > 0.f ? y[j] : 0.01f * y[j];
            *reinterpret_cast<f32x4*>(dst + t * 4) = y;
        }
    }
}

// ---------------------------------------------------------------------------
// Fallback path (round-1 structure).
// ---------------------------------------------------------------------------
__global__ __launch_bounds__(256) void conv_scatter_fb(const float* __restrict__ feats,
                                                       const unsigned short* __restrict__ wfrag,
                                                       const int* __restrict__ oidx,
                                                       float* __restrict__ out,
                                                       int Npts) {
    __shared__ unsigned short As[64 * 64];
    __shared__ int Is[64 * KVOL];
    const int tid  = threadIdx.x;
    const int base = blockIdx.x * 64;
    #pragma unroll
    for (int e = 0; e < 4; ++e) {
        int lin = e * 1024 + tid * 4;
        int row = lin >> 6, col = lin & 63;
        float4 v = make_float4(0.f, 0.f, 0.f, 0.f);
        if (base + row < Npts)
            v = *reinterpret_cast<const float4*>(feats + (size_t)(base + row) * 64 + col);
        As[lin + 0] = f2bf(v.x); As[lin + 1] = f2bf(v.y);
        As[lin + 2] = f2bf(v.z); As[lin + 3] = f2bf(v.w);
    }
    for (int lin = tid; lin < 64 * KVOL; lin += 256) {
        int g = base * KVOL + lin;
        Is[lin] = (g < Npts * KVOL) ? oidx[g] : 0;
    }
    __syncthreads();
    const int w = tid >> 6, l = tid & 63, cl = l & 15, hi = l >> 4;
    const v8bf a0 = *reinterpret_cast<const v8bf*>(&As[(16 * w + cl) * 64 + hi * 8]);
    const v8bf a1 = *reinterpret_cast<const v8bf*>(&As[(16 * w + cl) * 64 + 32 + hi * 8]);
    const v8bf* wf = reinterpret_cast<const v8bf*>(wfrag);
    for (int k = 0; k < KVOL; ++k) {
        f32x4 acc[4];
        #pragma unroll
        for (int t = 0; t < 4; ++t) acc[t] = (f32x4){0.f, 0.f, 0.f, 0.f};
        #pragma unroll
        for (int t = 0; t < 4; ++t) {
            v8bf b0 = wf[((k * 4 + t) * 2 + 0) * 64 + l];
            v8bf b1 = wf[((k * 4 + t) * 2 + 1) * 64 + l];
            acc[t] = __builtin_amdgcn_mfma_f32_16x16x32_bf16(b0, a0, acc[t], 0, 0, 0);
            acc[t] = __builtin_amdgcn_mfma_f32_16x16x32_bf16(b1, a1, acc[t], 0, 0, 0);
        }
        if ((base + 16 * w + cl) < Npts) {
            int o = Is[(16 * w + cl) * KVOL + k];
            float* dst = out + (size_t)o * 64 + hi * 4;
            #pragma unroll
            for (int t = 0; t < 4; ++t)
                #pragma unroll
                for (int j = 0; j < 4; ++j)
                    unsafeAtomicAdd(dst + t * 16 + j, acc[t][j]);
        }
    }
}

__global__ __launch_bounds__(256) void bn_stats(const float* __restrict__ out,
                                                float* __restrict__ stats,
                                                int Nout) {
    const int tid = threadIdx.x;
    const int cg  = tid & 15;
    const int rs  = tid >> 4;
    f32x4 s = {0.f, 0.f, 0.f, 0.f}, q = {0.f, 0.f, 0.f, 0.f};
    for (long r = (long)blockIdx.x * 16 + rs; r < Nout; r += (long)gridDim.x * 16) {
        f32x4 v = *reinterpret_cast<const f32x4*>(out + (size_t)r * 64 + cg * 4);
        s += v;
        q += v * v;
    }
    __shared__ f32x4 sd[256];
    __shared__ f32x4 qd[256];
    sd[tid] = s; qd[tid] = q;
    __syncthreads();
    #pragma unroll
    for (int st = 8; st >= 1; st >>= 1) {
        if (rs < st) { sd[tid] += sd[tid + 16 * st]; qd[tid] += qd[tid + 16 * st]; }
        __syncthreads();
    }
    if (rs == 0) {
        #pragma unroll
        for (int c = 0; c < 4; ++c) {
            unsafeAtomicAdd(&stats[cg * 4 + c],      sd[tid][c]);
            unsafeAtomicAdd(&stats[64 + cg * 4 + c], qd[tid][c]);
        }
    }
}

__global__ __launch_bounds__(256) void bn_apply(float* __restrict__ out,
                                                const float* __restrict__ stats,
                                                const float* __restrict__ gamma,
                                                const float* __restrict__ beta,
                                                int Nout) {
    const int tid = threadIdx.x;
    const int cg  = tid & 15;
    const int rs  = tid >> 4;
    const float inv = 1.0f / (float)Nout;
    f32x4 scale, shift;
    #pragma unroll
    for (int c = 0; c < 4; ++c) {
        float m   = stats[cg * 4 + c] * inv;
        float var = stats[64 + cg * 4 + c] * inv - m * m;
        float sc  = gamma[cg * 4 + c] * rsqrtf(var + 1e-5f);
        scale[c]  = sc;
        shift[c]  = beta[cg * 4 + c] - sc * m;
    }
    for (long r = (long)blockIdx.x * 16 + rs; r < Nout; r += (long)gridDim.x * 16) {
        f32x4* p = reinterpret_cast<f32x4*>(out + (size_t)r * 64 + cg * 4);
        f32x4 v = *p;
        v = v * scale + shift;
        #pragma unroll
        for (int c = 0; c < 4; ++c) v[c] = v[c] > 0.f ? v[c] : 0.01f * v[c];
        *p = v;
    }
}

static inline size_t al4k(size_t x) { return (x + 4095) & ~(size_t)4095; }

extern "C" void kernel_launch(void* const* d_in, const int* in_sizes, int n_in,
                              void* d_out, int out_size, void* d_ws, size_t ws_size,
                              hipStream_t stream) {
    const float* feats = (const float*)d_in[1];
    const float* W     = (const float*)d_in[2];
    const float* gamma = (const float*)d_in[3];
    const float* beta  = (const float*)d_in[4];
    const int*   oidx  = (const int*)d_in[5];
    float* out = (float*)d_out;

    const int Npts = in_sizes[1] / 64;   // 100000
    const int Nout = out_size / 64;      // ~2.51M
    const int M    = Npts * KVOL;
    const int nb   = (Nout + SCB - 1) / SCB;

    // Workspace layout
    char* ws = (char*)d_ws;
    float* stats  = (float*)ws;                            // 512 B
    float* colsum = (float*)(ws + 512);                    // 256 B
    float* S      = (float*)(ws + 4096);                   // 16 KiB
    unsigned short* wfrag = (unsigned short*)(ws + 32768); // 216 KiB
    int* hist = (int*)(ws + 262144);                       // 64 KiB
    int* perm = (int*)(ws + 327680);                       // Npts*4
    size_t o1 = al4k(327680 + (size_t)Npts * 4);
    int* cnt    = (int*)(ws + o1);                         // Nout*4
    size_t o2 = al4k(o1 + (size_t)Nout * 4);
    int* rowptr = (int*)(ws + o2);                         // Nout*4
    size_t o3 = al4k(o2 + (size_t)Nout * 4);
    int* cursor = (int*)(ws + o3);                         // Nout*4
    size_t o4 = al4k(o3 + (size_t)Nout * 4);
    int* psums  = (int*)(ws + o4);                         // nb*4
    size_t o5 = al4k(o4 + (size_t)nb * 4);
    int* ent    = (int*)(ws + o5);                         // M*4
    const size_t ws_need = o5 + (size_t)M * 4;

    const int pgrid = (Npts + 255) / 256;
    const int ggrid = (Nout + GR - 1) / GR;

    if (ws_size >= ws_need) {
        hipMemsetAsync(ws, 0, 32768, stream);              // stats+colsum+S
        hipMemsetAsync(hist, 0, NBKT * sizeof(int), stream);
        hipMemsetAsync(cnt, 0, (size_t)Nout * sizeof(int), stream);
        hipLaunchKernelGGL(prep_kernel, dim3(432), dim3(256), 0, stream, W, wfrag, stats);
        hipLaunchKernelGGL(hist_kernel, dim3(pgrid), dim3(256), 0, stream, oidx, hist, Npts, Nout);
        hipLaunchKernelGGL(count_kernel, dim3(2048), dim3(256), 0, stream, oidx, cnt, M);
        hipLaunchKernelGGL(scan_hist, dim3(1), dim3(256), 0, stream, hist);
        hipLaunchKernelGGL(perm_fill, dim3(pgrid), dim3(256), 0, stream, oidx, hist, perm, Npts, Nout);
        hipLaunchKernelGGL(scan_part, dim3(nb), dim3(256), 0, stream, cnt, psums, Nout);
        hipLaunchKernelGGL(scan_psums, dim3(1), dim3(256), 0, stream, psums, nb);
        hipLaunchKernelGGL(scan_write, dim3(nb), dim3(256), 0, stream, cnt, psums, rowptr, cursor, Nout);
        hipLaunchKernelGGL(fill_ent, dim3(pgrid), dim3(256), 0, stream, oidx, perm, cursor, ent, Npts);
        hipLaunchKernelGGL(feat_stats, dim3(256), dim3(256), 0, stream, feats, colsum, S, Npts);
        hipLaunchKernelGGL(qall_mean, dim3(KVOL), dim3(64), 0, stream, W, colsum, S, stats);
        hipLaunchKernelGGL(gather_conv_bn, dim3(ggrid), dim3(256), 0, stream,
                           feats, wfrag, rowptr, ent, stats, gamma, beta, out, Nout, M);
    } else {
        hipMemsetAsync(d_out, 0, (size_t)out_size * sizeof(float), stream);
        hipMemsetAsync(ws, 0, 512, stream);
        hipLaunchKernelGGL(prep_kernel, dim3(432), dim3(256), 0, stream, W, wfrag, stats);
        int cgrid = (Npts + 63) / 64;
        hipLaunchKernelGGL(conv_scatter_fb, dim3(cgrid), dim3(256), 0, stream,
                           feats, wfrag, oidx, out, Npts);
        hipLaunchKernelGGL(bn_stats, dim3(2048), dim3(256), 0, stream, out, stats, Nout);
        hipLaunchKernelGGL(bn_apply, dim3(2048), dim3(256), 0, stream, out, stats, gamma, beta, Nout);
    }
}

// Round 12
// 398.662 us; speedup vs baseline: 3.7456x; 3.7456x over previous
//
#include <hip/hip_runtime.h>
#include <hip/hip_bf16.h>

typedef __bf16 v8bf __attribute__((ext_vector_type(8)));
typedef float  f32x4 __attribute__((ext_vector_type(4)));

#define KVOL 27
#define KG   4   // taps staged to LDS per group

__device__ __forceinline__ unsigned short f2bf(float f) {
    unsigned int u = __float_as_uint(f);
    u = u + 0x7FFFu + ((u >> 16) & 1u);   // round-to-nearest-even
    return (unsigned short)(u >> 16);
}
__device__ __forceinline__ float bf2f(unsigned short u) {
    return __uint_as_float((unsigned int)u << 16);
}

// ---------------------------------------------------------------------------
// Prep: W [27][64in][64out] fp32 -> bf16 MFMA fragments.
// lane l, elem i holds W[k][s*32+(l>>4)*8+i][t*16+(l&15)]
// at ushort index (((k*4+t)*2+s)*64 + l)*8 + i.
// ---------------------------------------------------------------------------
__global__ __launch_bounds__(256) void prep_kernel(const float* __restrict__ W,
                                                   unsigned short* __restrict__ wfrag) {
    int d = blockIdx.x * 256 + threadIdx.x;
    if (d < KVOL * 64 * 64) {
        int i    = d & 7;
        int lane = (d >> 3) & 63;
        int s    = (d >> 9) & 1;
        int t    = (d >> 10) & 3;
        int k    = d >> 12;
        int kin  = s * 32 + (lane >> 4) * 8 + i;
        int c    = t * 16 + (lane & 15);
        wfrag[d] = f2bf(W[k * 4096 + kin * 64 + c]);
    }
}

__global__ __launch_bounds__(256) void count_kernel(const int* __restrict__ oidx,
                                                    int* __restrict__ cnt, int M) {
    for (int e = blockIdx.x * 256 + threadIdx.x; e < M; e += gridDim.x * 256)
        atomicAdd(&cnt[oidx[e]], 1);
}

// Zero only multi-contributor rows (cnt >= 2). 4 threads per row.
__global__ __launch_bounds__(256) void zero_multi(float* __restrict__ out,
                                                  const int* __restrict__ cnt, int Nout) {
    const int sub = threadIdx.x & 3;
    const long step = (long)gridDim.x * 64;
    for (long r = (long)blockIdx.x * 64 + (threadIdx.x >> 2); r < Nout; r += step) {
        if (cnt[r] > 1) {
            f32x4 z = {0.f, 0.f, 0.f, 0.f};
            f32x4* p = reinterpret_cast<f32x4*>(out + r * 64) + sub;
            p[0] = z; p[4] = z; p[8] = z; p[12] = z;
        }
    }
}

// ---------------------------------------------------------------------------
// feat_stats: colsum[64] and S = feats^T feats (bf16 MFMA, fp32 accum).
// Numerically matches the bf16 conv path (validated in R7).
// ---------------------------------------------------------------------------
__global__ __launch_bounds__(256) void feat_stats(const float* __restrict__ feats,
                                                  float* __restrict__ colsum,
                                                  float* __restrict__ S,
                                                  int Npts) {
    __shared__ unsigned short As[128 * 64];
    const int tid = threadIdx.x;
    const int w = tid >> 6, l = tid & 63, cl = l & 15, hi = l >> 4;
    const int c = tid & 63, rg = tid >> 6;
    const __bf16* Ab = reinterpret_cast<const __bf16*>(As);

    f32x4 acc[4][4];
    #pragma unroll
    for (int a = 0; a < 4; ++a)
        #pragma unroll
        for (int b = 0; b < 4; ++b) acc[a][b] = (f32x4){0.f, 0.f, 0.f, 0.f};
    float csum = 0.f;

    for (int base = blockIdx.x * 128; base < Npts; base += gridDim.x * 128) {
        __syncthreads();
        #pragma unroll
        for (int e = 0; e < 8; ++e) {
            int lin4 = e * 256 + tid;
            int row = lin4 >> 4, col = (lin4 & 15) * 4;
            float4 v = make_float4(0.f, 0.f, 0.f, 0.f);
            if (base + row < Npts)
                v = *reinterpret_cast<const float4*>(feats + (size_t)(base + row) * 64 + col);
            int o = row * 64 + col;
            As[o + 0] = f2bf(v.x); As[o + 1] = f2bf(v.y);
            As[o + 2] = f2bf(v.z); As[o + 3] = f2bf(v.w);
        }
        __syncthreads();
        for (int r = 0; r < 32; ++r) csum += bf2f(As[(rg * 32 + r) * 64 + c]);
        v8bf f[4];
        #pragma unroll
        for (int t = 0; t < 4; ++t)
            #pragma unroll
            for (int i = 0; i < 8; ++i)
                f[t][i] = Ab[(w * 32 + hi * 8 + i) * 64 + cl + 16 * t];
        #pragma unroll
        for (int a = 0; a < 4; ++a)
            #pragma unroll
            for (int b = 0; b < 4; ++b)
                acc[a][b] = __builtin_amdgcn_mfma_f32_16x16x32_bf16(f[a], f[b], acc[a][b], 0, 0, 0);
    }

    unsafeAtomicAdd(&colsum[c], csum);
    #pragma unroll
    for (int a = 0; a < 4; ++a)
        #pragma unroll
        for (int b = 0; b < 4; ++b)
            #pragma unroll
            for (int r = 0; r < 4; ++r) {
                int i = a * 16 + hi * 4 + r;
                int j = b * 16 + cl;
                unsafeAtomicAdd(&S[i * 64 + j], acc[a][b][r]);
            }
}

// qall_mean: per tap k (block), channel c (thread):
//   stats[64+c] += w_kc^T S w_kc   (sum of squared contributions)
//   stats[c]    += colsum . w_kc   (exact sum, by linearity)
__global__ __launch_bounds__(64) void qall_mean(const float* __restrict__ W,
                                                const float* __restrict__ colsum,
                                                const float* __restrict__ S,
                                                float* __restrict__ stats) {
    __shared__ float Sl[4096];
    __shared__ float Wl[4096];
    __shared__ float cs[64];
    const int tid = threadIdx.x;
    const int k = blockIdx.x;
    for (int lin = tid; lin < 4096; lin += 64) {
        Sl[lin] = S[lin];
        Wl[lin] = W[k * 4096 + lin];
    }
    cs[tid] = colsum[tid];
    __syncthreads();
    const int c = tid;
    float q = 0.f, sm = 0.f;
    for (int i = 0; i < 64; ++i) {
        float wi = Wl[i * 64 + c];
        sm += cs[i] * wi;
        float d = 0.f;
        #pragma unroll 8
        for (int j = 0; j < 64; ++j) d += Sl[i * 64 + j] * Wl[j * 64 + c];
        q += wi * d;
    }
    unsafeAtomicAdd(&stats[64 + c], q);
    unsafeAtomicAdd(&stats[c], sm);
}

// Stage bf16 A tile from fp32 feats (natural order).
__device__ __forceinline__ void stage_A(const float* __restrict__ feats,
                                        unsigned short* As, int base, int Npts) {
    const int tid = threadIdx.x;
    #pragma unroll
    for (int e = 0; e < 4; ++e) {
        int lin = e * 1024 + tid * 4;
        int row = lin >> 6, col = lin & 63;
        float4 v = make_float4(0.f, 0.f, 0.f, 0.f);
        if (base + row < Npts)
            v = *reinterpret_cast<const float4*>(feats + (size_t)(base + row) * 64 + col);
        As[lin + 0] = f2bf(v.x);
        As[lin + 1] = f2bf(v.y);
        As[lin + 2] = f2bf(v.z);
        As[lin + 3] = f2bf(v.w);
    }
}

// ---------------------------------------------------------------------------
// THE single conv pass. Swapped-operand MFMA: lane (hi,cl) holds channels
// t*16+hi*4+{0..3} of point-row cl. W LDS-staged in KG-tap groups.
// Single rows: BN+LeakyReLU in-register -> plain dwordx4 store.
// Multi rows: raw (pre-BN) atomicAdd; BN'd later by multi_apply.
// ---------------------------------------------------------------------------
__global__ __launch_bounds__(256) void conv_fused(const float* __restrict__ feats,
                                                  const unsigned short* __restrict__ wfrag,
                                                  const int* __restrict__ oidx,
                                                  const int* __restrict__ cnt,
                                                  const float* __restrict__ stats,
                                                  const float* __restrict__ gamma,
                                                  const float* __restrict__ beta,
                                                  float* __restrict__ out,
                                                  int Npts, int Nout) {
    __shared__ unsigned short As[64 * 64];
    __shared__ int Is[64 * KVOL];
    __shared__ unsigned short Ws[KG * 4096];

    const int tid  = threadIdx.x;
    const int base = blockIdx.x * 64;
    const int M    = Npts * KVOL;

    stage_A(feats, As, base, Npts);
    for (int lin = tid; lin < 64 * KVOL; lin += 256) {
        int g = base * KVOL + lin;
        int iv = 0;
        if (g < M) {
            int o = oidx[g];
            iv = o | (cnt[o] > 1 ? 0x80000000 : 0);
        }
        Is[lin] = iv;
    }
    __syncthreads();

    const int w = tid >> 6, l = tid & 63, cl = l & 15, hi = l >> 4;
    const bool valid = (base + 16 * w + cl) < Npts;
    const v8bf a0 = *reinterpret_cast<const v8bf*>(&As[(16 * w + cl) * 64 + hi * 8]);
    const v8bf a1 = *reinterpret_cast<const v8bf*>(&As[(16 * w + cl) * 64 + 32 + hi * 8]);
    const v8bf* wfv = reinterpret_cast<const v8bf*>(wfrag);
    v8bf*       Wv  = reinterpret_cast<v8bf*>(Ws);
    const v8bf* Wl  = reinterpret_cast<const v8bf*>(Ws);

    const float inv = 1.0f / (float)Nout;
    f32x4 scale4[4], shift4[4];
    #pragma unroll
    for (int t = 0; t < 4; ++t) {
        int c0 = t * 16 + hi * 4;
        f32x4 m4 = *reinterpret_cast<const f32x4*>(stats + c0);
        f32x4 v4 = *reinterpret_cast<const f32x4*>(stats + 64 + c0);
        f32x4 g4 = *reinterpret_cast<const f32x4*>(gamma + c0);
        f32x4 b4 = *reinterpret_cast<const f32x4*>(beta + c0);
        #pragma unroll
        for (int j = 0; j < 4; ++j) {
            float m   = m4[j] * inv;
            float var = v4[j] * inv - m * m;
            float sc  = g4[j] * rsqrtf(var + 1e-5f);
            scale4[t][j] = sc;
            shift4[t][j] = b4[j] - sc * m;
        }
    }

    for (int k0 = 0; k0 < KVOL; k0 += KG) {
        const int kn = (KVOL - k0) < KG ? (KVOL - k0) : KG;
        __syncthreads();
        for (int j = tid; j < kn * 512; j += 256)
            Wv[j] = wfv[k0 * 512 + j];
        __syncthreads();

        for (int dk = 0; dk < kn; ++dk) {
            const int k = k0 + dk;
            f32x4 acc[4];
            #pragma unroll
            for (int t = 0; t < 4; ++t) acc[t] = (f32x4){0.f, 0.f, 0.f, 0.f};
            #pragma unroll
            for (int t = 0; t < 4; ++t) {
                v8bf b0 = Wl[((dk * 4 + t) * 2 + 0) * 64 + l];
                v8bf b1 = Wl[((dk * 4 + t) * 2 + 1) * 64 + l];
                acc[t] = __builtin_amdgcn_mfma_f32_16x16x32_bf16(b0, a0, acc[t], 0, 0, 0);
                acc[t] = __builtin_amdgcn_mfma_f32_16x16x32_bf16(b1, a1, acc[t], 0, 0, 0);
            }
            if (valid) {
                int iv = Is[(16 * w + cl) * KVOL + k];
                if (iv >= 0) {                 // single row: finalize now
                    float* dst = out + (size_t)iv * 64 + hi * 4;
                    #pragma unroll
                    for (int t = 0; t < 4; ++t) {
                        f32x4 y = acc[t] * scale4[t] + shift4[t];
                        #pragma unroll
                        for (int j = 0; j < 4; ++j) y[j] = y[j] > 0.f ? y[j] : 0.01f * y[j];
                        *reinterpret_cast<f32x4*>(dst + t * 16) = y;
                    }
                } else {                       // multi row: raw accumulate
                    int o = iv & 0x7fffffff;
                    float* dst = out + (size_t)o * 64 + hi * 4;
                    #pragma unroll
                    for (int t = 0; t < 4; ++t)
                        #pragma unroll
                        for (int j = 0; j < 4; ++j)
                            unsafeAtomicAdd(dst + t * 16 + j, acc[t][j]);
                }
            }
        }
    }
}

// BN+LeakyReLU in place for multi rows.
__global__ __launch_bounds__(256) void multi_apply(float* __restrict__ out,
                                                   const int* __restrict__ cnt,
                                                   const float* __restrict__ stats,
                                                   const float* __restrict__ gamma,
                                                   const float* __restrict__ beta,
                                                   int Nout) {
    const int tid = threadIdx.x;
    const int cg  = tid & 15;
    const int rs  = tid >> 4;
    const float inv = 1.0f / (float)Nout;
    f32x4 scale, shift;
    #pragma unroll
    for (int c = 0; c < 4; ++c) {
        float m   = stats[cg * 4 + c] * inv;
        float var = stats[64 + cg * 4 + c] * inv - m * m;
        float sc  = gamma[cg * 4 + c] * rsqrtf(var + 1e-5f);
        scale[c]  = sc;
        shift[c]  = beta[cg * 4 + c] - sc * m;
    }
    for (long r = (long)blockIdx.x * 16 + rs; r < Nout; r += (long)gridDim.x * 16) {
        if (cnt[r] > 1) {
            f32x4* p = reinterpret_cast<f32x4*>(out + (size_t)r * 64 + cg * 4);
            f32x4 v = *p;
            v = v * scale + shift;
            #pragma unroll
            for (int c = 0; c < 4; ++c) v[c] = v[c] > 0.f ? v[c] : 0.01f * v[c];
            *p = v;
        }
    }
}

// ---------------------------------------------------------------------------
// Fallback path (round-1 structure).
// ---------------------------------------------------------------------------
__global__ __launch_bounds__(256) void conv_scatter_fb(const float* __restrict__ feats,
                                                       const unsigned short* __restrict__ wfrag,
                                                       const int* __restrict__ oidx,
                                                       float* __restrict__ out,
                                                       int Npts) {
    __shared__ unsigned short As[64 * 64];
    __shared__ int Is[64 * KVOL];
    const int tid  = threadIdx.x;
    const int base = blockIdx.x * 64;
    stage_A(feats, As, base, Npts);
    for (int lin = tid; lin < 64 * KVOL; lin += 256) {
        int g = base * KVOL + lin;
        Is[lin] = (g < Npts * KVOL) ? oidx[g] : 0;
    }
    __syncthreads();
    const int w = tid >> 6, l = tid & 63, cl = l & 15, hi = l >> 4;
    const v8bf a0 = *reinterpret_cast<const v8bf*>(&As[(16 * w + cl) * 64 + hi * 8]);
    const v8bf a1 = *reinterpret_cast<const v8bf*>(&As[(16 * w + cl) * 64 + 32 + hi * 8]);
    const v8bf* wf = reinterpret_cast<const v8bf*>(wfrag);
    for (int k = 0; k < KVOL; ++k) {
        f32x4 acc[4];
        #pragma unroll
        for (int t = 0; t < 4; ++t) acc[t] = (f32x4){0.f, 0.f, 0.f, 0.f};
        #pragma unroll
        for (int t = 0; t < 4; ++t) {
            v8bf b0 = wf[((k * 4 + t) * 2 + 0) * 64 + l];
            v8bf b1 = wf[((k * 4 + t) * 2 + 1) * 64 + l];
            acc[t] = __builtin_amdgcn_mfma_f32_16x16x32_bf16(b0, a0, acc[t], 0, 0, 0);
            acc[t] = __builtin_amdgcn_mfma_f32_16x16x32_bf16(b1, a1, acc[t], 0, 0, 0);
        }
        if ((base + 16 * w + cl) < Npts) {
            int o = Is[(16 * w + cl) * KVOL + k];
            float* dst = out + (size_t)o * 64 + hi * 4;
            #pragma unroll
            for (int t = 0; t < 4; ++t)
                #pragma unroll
                for (int j = 0; j < 4; ++j)
                    unsafeAtomicAdd(dst + t * 16 + j, acc[t][j]);
        }
    }
}

__global__ __launch_bounds__(256) void bn_stats(const float* __restrict__ out,
                                                float* __restrict__ stats,
                                                int Nout) {
    const int tid = threadIdx.x;
    const int cg  = tid & 15;
    const int rs  = tid >> 4;
    f32x4 s = {0.f, 0.f, 0.f, 0.f}, q = {0.f, 0.f, 0.f, 0.f};
    for (long r = (long)blockIdx.x * 16 + rs; r < Nout; r += (long)gridDim.x * 16) {
        f32x4 v = *reinterpret_cast<const f32x4*>(out + (size_t)r * 64 + cg * 4);
        s += v;
        q += v * v;
    }
    __shared__ f32x4 sd[256];
    __shared__ f32x4 qd[256];
    sd[tid] = s; qd[tid] = q;
    __syncthreads();
    #pragma unroll
    for (int st = 8; st >= 1; st >>= 1) {
        if (rs < st) { sd[tid] += sd[tid + 16 * st]; qd[tid] += qd[tid + 16 * st]; }
        __syncthreads();
    }
    if (rs == 0) {
        #pragma unroll
        for (int c = 0; c < 4; ++c) {
            unsafeAtomicAdd(&stats[cg * 4 + c],      sd[tid][c]);
            unsafeAtomicAdd(&stats[64 + cg * 4 + c], qd[tid][c]);
        }
    }
}

__global__ __launch_bounds__(256) void bn_apply(float* __restrict__ out,
                                                const float* __restrict__ stats,
                                                const float* __restrict__ gamma,
                                                const float* __restrict__ beta,
                                                int Nout) {
    const int tid = threadIdx.x;
    const int cg  = tid & 15;
    const int rs  = tid >> 4;
    const float inv = 1.0f / (float)Nout;
    f32x4 scale, shift;
    #pragma unroll
    for (int c = 0; c < 4; ++c) {
        float m   = stats[cg * 4 + c] * inv;
        float var = stats[64 + cg * 4 + c] * inv - m * m;
        float sc  = gamma[cg * 4 + c] * rsqrtf(var + 1e-5f);
        scale[c]  = sc;
        shift[c]  = beta[cg * 4 + c] - sc * m;
    }
    for (long r = (long)blockIdx.x * 16 + rs; r < Nout; r += (long)gridDim.x * 16) {
        f32x4* p = reinterpret_cast<f32x4*>(out + (size_t)r * 64 + cg * 4);
        f32x4 v = *p;
        v = v * scale + shift;
        #pragma unroll
        for (int c = 0; c < 4; ++c) v[c] = v[c] > 0.f ? v[c] : 0.01f * v[c];
        *p = v;
    }
}

extern "C" void kernel_launch(void* const* d_in, const int* in_sizes, int n_in,
                              void* d_out, int out_size, void* d_ws, size_t ws_size,
                              hipStream_t stream) {
    const float* feats = (const float*)d_in[1];
    const float* W     = (const float*)d_in[2];
    const float* gamma = (const float*)d_in[3];
    const float* beta  = (const float*)d_in[4];
    const int*   oidx  = (const int*)d_in[5];
    float* out = (float*)d_out;

    const int Npts = in_sizes[1] / 64;   // 100000
    const int Nout = out_size / 64;      // ~2.51M
    const int M    = Npts * KVOL;

    // Workspace layout (~10.5 MB)
    char* ws = (char*)d_ws;
    float* stats  = (float*)ws;                            // 512 B
    float* colsum = (float*)(ws + 512);                    // 256 B
    float* S      = (float*)(ws + 4096);                   // 16 KiB
    unsigned short* wfrag = (unsigned short*)(ws + 32768); // 216 KiB
    int* cnt = (int*)(ws + 262144);                        // Nout*4
    const size_t ws_need = 262144 + (size_t)Nout * 4;

    const int cgrid = (Npts + 63) / 64;

    if (ws_size >= ws_need) {
        hipMemsetAsync(ws, 0, 32768, stream);              // stats + colsum + S
        hipMemsetAsync(cnt, 0, (size_t)Nout * sizeof(int), stream);
        hipLaunchKernelGGL(prep_kernel, dim3(432), dim3(256), 0, stream, W, wfrag);
        hipLaunchKernelGGL(count_kernel, dim3(2048), dim3(256), 0, stream, oidx, cnt, M);
        hipLaunchKernelGGL(feat_stats, dim3(256), dim3(256), 0, stream, feats, colsum, S, Npts);
        hipLaunchKernelGGL(qall_mean, dim3(KVOL), dim3(64), 0, stream, W, colsum, S, stats);
        hipLaunchKernelGGL(zero_multi, dim3(2048), dim3(256), 0, stream, out, cnt, Nout);
        hipLaunchKernelGGL(conv_fused, dim3(cgrid), dim3(256), 0, stream,
                           feats, wfrag, oidx, cnt, stats, gamma, beta, out, Npts, Nout);
        hipLaunchKernelGGL(multi_apply, dim3(2048), dim3(256), 0, stream,
                           out, cnt, stats, gamma, beta, Nout);
    } else {
        hipMemsetAsync(d_out, 0, (size_t)out_size * sizeof(float), stream);
        hipMemsetAsync(ws, 0, 512, stream);
        hipLaunchKernelGGL(prep_kernel, dim3(432), dim3(256), 0, stream, W, wfrag);
        hipLaunchKernelGGL(conv_scatter_fb, dim3(cgrid), dim3(256), 0, stream,
                           feats, wfrag, oidx, out, Npts);
        hipLaunchKernelGGL(bn_stats, dim3(2048), dim3(256), 0, stream, out, stats, Nout);
        hipLaunchKernelGGL(bn_apply, dim3(2048), dim3(256), 0, stream, out, stats, gamma, beta, Nout);
    }
}

// Round 13
// 365.271 us; speedup vs baseline: 4.0880x; 1.0914x over previous
//
#include <hip/hip_runtime.h>
#include <hip/hip_bf16.h>

typedef __bf16 v8bf __attribute__((ext_vector_type(8)));
typedef float  f32x4 __attribute__((ext_vector_type(4)));

#define KVOL 27
#define KG   2      // taps staged to LDS per group (31.5KB LDS -> 5 blocks/CU)
#define NB_PREP 432
#define NB_CNT  2048
#define NB_FS   256
#define NB_Q    KVOL
#define NB_ZM   2048

__device__ __forceinline__ unsigned short f2bf(float f) {
    unsigned int u = __float_as_uint(f);
    u = u + 0x7FFFu + ((u >> 16) & 1u);   // round-to-nearest-even
    return (unsigned short)(u >> 16);
}
__device__ __forceinline__ float bf2f(unsigned short u) {
    return __uint_as_float((unsigned int)u << 16);
}

// ---------------------------------------------------------------------------
// pre_all: three independent jobs fused into one launch, selected by block id.
//   [0, NB_PREP)          : W -> bf16 MFMA fragments
//   [NB_PREP, +NB_CNT)    : count contributions per output row
//   [.., +NB_FS)          : feat_stats (colsum, S = feats^T feats via MFMA)
// ---------------------------------------------------------------------------
__global__ __launch_bounds__(256) void pre_all(const float* __restrict__ W,
                                               unsigned short* __restrict__ wfrag,
                                               const int* __restrict__ oidx,
                                               int* __restrict__ cnt,
                                               const float* __restrict__ feats,
                                               float* __restrict__ colsum,
                                               float* __restrict__ S,
                                               int Npts) {
    __shared__ unsigned short As[128 * 64];
    const int tid = threadIdx.x;
    const int bx  = blockIdx.x;
    const int M   = Npts * KVOL;

    if (bx < NB_PREP) {
        int d = bx * 256 + tid;
        if (d < KVOL * 64 * 64) {
            int i    = d & 7;
            int lane = (d >> 3) & 63;
            int s    = (d >> 9) & 1;
            int t    = (d >> 10) & 3;
            int k    = d >> 12;
            int kin  = s * 32 + (lane >> 4) * 8 + i;
            int c    = t * 16 + (lane & 15);
            wfrag[d] = f2bf(W[k * 4096 + kin * 64 + c]);
        }
        return;
    }
    if (bx < NB_PREP + NB_CNT) {
        int b = bx - NB_PREP;
        for (int e = b * 256 + tid; e < M; e += NB_CNT * 256)
            atomicAdd(&cnt[oidx[e]], 1);
        return;
    }
    // feat_stats
    {
        const int b = bx - (NB_PREP + NB_CNT);
        const int w = tid >> 6, l = tid & 63, cl = l & 15, hi = l >> 4;
        const int c = tid & 63, rg = tid >> 6;
        const __bf16* Ab = reinterpret_cast<const __bf16*>(As);

        f32x4 acc[4][4];
        #pragma unroll
        for (int a = 0; a < 4; ++a)
            #pragma unroll
            for (int bb = 0; bb < 4; ++bb) acc[a][bb] = (f32x4){0.f, 0.f, 0.f, 0.f};
        float csum = 0.f;

        for (int base = b * 128; base < Npts; base += NB_FS * 128) {
            __syncthreads();
            #pragma unroll
            for (int e = 0; e < 8; ++e) {
                int lin4 = e * 256 + tid;
                int row = lin4 >> 4, col = (lin4 & 15) * 4;
                float4 v = make_float4(0.f, 0.f, 0.f, 0.f);
                if (base + row < Npts)
                    v = *reinterpret_cast<const float4*>(feats + (size_t)(base + row) * 64 + col);
                int o = row * 64 + col;
                As[o + 0] = f2bf(v.x); As[o + 1] = f2bf(v.y);
                As[o + 2] = f2bf(v.z); As[o + 3] = f2bf(v.w);
            }
            __syncthreads();
            for (int r = 0; r < 32; ++r) csum += bf2f(As[(rg * 32 + r) * 64 + c]);
            v8bf f[4];
            #pragma unroll
            for (int t = 0; t < 4; ++t)
                #pragma unroll
                for (int i = 0; i < 8; ++i)
                    f[t][i] = Ab[(w * 32 + hi * 8 + i) * 64 + cl + 16 * t];
            #pragma unroll
            for (int a = 0; a < 4; ++a)
                #pragma unroll
                for (int bb = 0; bb < 4; ++bb)
                    acc[a][bb] = __builtin_amdgcn_mfma_f32_16x16x32_bf16(f[a], f[bb], acc[a][bb], 0, 0, 0);
        }

        unsafeAtomicAdd(&colsum[c], csum);
        #pragma unroll
        for (int a = 0; a < 4; ++a)
            #pragma unroll
            for (int bb = 0; bb < 4; ++bb)
                #pragma unroll
                for (int r = 0; r < 4; ++r) {
                    int i = a * 16 + hi * 4 + r;
                    int j = bb * 16 + cl;
                    unsafeAtomicAdd(&S[i * 64 + j], acc[a][bb][r]);
                }
    }
}

// ---------------------------------------------------------------------------
// mid_all: two independent jobs fused:
//   [0, NB_Q)   : qall_mean — stats[c] += colsum.w ; stats[64+c] += w^T S w
//   [NB_Q, ..)  : zero_multi — zero rows with cnt >= 2
// ---------------------------------------------------------------------------
__global__ __launch_bounds__(256) void mid_all(const float* __restrict__ W,
                                               const float* __restrict__ colsum,
                                               const float* __restrict__ S,
                                               float* __restrict__ stats,
                                               float* __restrict__ out,
                                               const int* __restrict__ cnt,
                                               int Nout) {
    __shared__ float Sl[4096];
    __shared__ float Wl[4096];
    __shared__ float cs[64];
    const int tid = threadIdx.x;
    const int bx  = blockIdx.x;

    if (bx < NB_Q) {
        const int k = bx;
        for (int lin = tid; lin < 4096; lin += 256) {
            Sl[lin] = S[lin];
            Wl[lin] = W[k * 4096 + lin];
        }
        if (tid < 64) cs[tid] = colsum[tid];
        __syncthreads();
        if (tid < 64) {
            const int c = tid;
            float q = 0.f, sm = 0.f;
            for (int i = 0; i < 64; ++i) {
                float wi = Wl[i * 64 + c];
                sm += cs[i] * wi;
                float d = 0.f;
                #pragma unroll 8
                for (int j = 0; j < 64; ++j) d += Sl[i * 64 + j] * Wl[j * 64 + c];
                q += wi * d;
            }
            unsafeAtomicAdd(&stats[64 + c], q);
            unsafeAtomicAdd(&stats[c], sm);
        }
        return;
    }
    // zero_multi
    {
        const int b = bx - NB_Q;
        const int sub = tid & 3;
        const long step = (long)NB_ZM * 64;
        for (long r = (long)b * 64 + (tid >> 2); r < Nout; r += step) {
            if (cnt[r] > 1) {
                f32x4 z = {0.f, 0.f, 0.f, 0.f};
                f32x4* p = reinterpret_cast<f32x4*>(out + r * 64) + sub;
                p[0] = z; p[4] = z; p[8] = z; p[12] = z;
            }
        }
    }
}

// Stage bf16 A tile from fp32 feats (natural order).
__device__ __forceinline__ void stage_A(const float* __restrict__ feats,
                                        unsigned short* As, int base, int Npts) {
    const int tid = threadIdx.x;
    #pragma unroll
    for (int e = 0; e < 4; ++e) {
        int lin = e * 1024 + tid * 4;
        int row = lin >> 6, col = lin & 63;
        float4 v = make_float4(0.f, 0.f, 0.f, 0.f);
        if (base + row < Npts)
            v = *reinterpret_cast<const float4*>(feats + (size_t)(base + row) * 64 + col);
        As[lin + 0] = f2bf(v.x);
        As[lin + 1] = f2bf(v.y);
        As[lin + 2] = f2bf(v.z);
        As[lin + 3] = f2bf(v.w);
    }
}

// ---------------------------------------------------------------------------
// THE single conv pass. Swapped-operand MFMA: lane (hi,cl) holds channels
// t*16+hi*4+{0..3} of point-row cl. W LDS-staged in KG-tap groups.
// Single rows: BN+LeakyReLU in-register -> plain dwordx4 store.
// Multi rows: raw (pre-BN) atomicAdd; BN'd later by multi_apply.
// ---------------------------------------------------------------------------
__global__ __launch_bounds__(256) void conv_fused(const float* __restrict__ feats,
                                                  const unsigned short* __restrict__ wfrag,
                                                  const int* __restrict__ oidx,
                                                  const int* __restrict__ cnt,
                                                  const float* __restrict__ stats,
                                                  const float* __restrict__ gamma,
                                                  const float* __restrict__ beta,
                                                  float* __restrict__ out,
                                                  int Npts, int Nout) {
    __shared__ unsigned short As[64 * 64];
    __shared__ int Is[64 * KVOL];
    __shared__ unsigned short Ws[KG * 4096];

    const int tid  = threadIdx.x;
    const int base = blockIdx.x * 64;
    const int M    = Npts * KVOL;

    stage_A(feats, As, base, Npts);
    for (int lin = tid; lin < 64 * KVOL; lin += 256) {
        int g = base * KVOL + lin;
        int iv = 0;
        if (g < M) {
            int o = oidx[g];
            iv = o | (cnt[o] > 1 ? 0x80000000 : 0);
        }
        Is[lin] = iv;
    }
    __syncthreads();

    const int w = tid >> 6, l = tid & 63, cl = l & 15, hi = l >> 4;
    const bool valid = (base + 16 * w + cl) < Npts;
    const v8bf a0 = *reinterpret_cast<const v8bf*>(&As[(16 * w + cl) * 64 + hi * 8]);
    const v8bf a1 = *reinterpret_cast<const v8bf*>(&As[(16 * w + cl) * 64 + 32 + hi * 8]);
    const v8bf* wfv = reinterpret_cast<const v8bf*>(wfrag);
    v8bf*       Wv  = reinterpret_cast<v8bf*>(Ws);
    const v8bf* Wl  = reinterpret_cast<const v8bf*>(Ws);

    const float inv = 1.0f / (float)Nout;
    f32x4 scale4[4], shift4[4];
    #pragma unroll
    for (int t = 0; t < 4; ++t) {
        int c0 = t * 16 + hi * 4;
        f32x4 m4 = *reinterpret_cast<const f32x4*>(stats + c0);
        f32x4 v4 = *reinterpret_cast<const f32x4*>(stats + 64 + c0);
        f32x4 g4 = *reinterpret_cast<const f32x4*>(gamma + c0);
        f32x4 b4 = *reinterpret_cast<const f32x4*>(beta + c0);
        #pragma unroll
        for (int j = 0; j < 4; ++j) {
            float m   = m4[j] * inv;
            float var = v4[j] * inv - m * m;
            float sc  = g4[j] * rsqrtf(var + 1e-5f);
            scale4[t][j] = sc;
            shift4[t][j] = b4[j] - sc * m;
        }
    }

    for (int k0 = 0; k0 < KVOL; k0 += KG) {
        const int kn = (KVOL - k0) < KG ? (KVOL - k0) : KG;
        __syncthreads();
        for (int j = tid; j < kn * 512; j += 256)
            Wv[j] = wfv[k0 * 512 + j];
        __syncthreads();

        for (int dk = 0; dk < kn; ++dk) {
            const int k = k0 + dk;
            f32x4 acc[4];
            #pragma unroll
            for (int t = 0; t < 4; ++t) acc[t] = (f32x4){0.f, 0.f, 0.f, 0.f};
            #pragma unroll
            for (int t = 0; t < 4; ++t) {
                v8bf b0 = Wl[((dk * 4 + t) * 2 + 0) * 64 + l];
                v8bf b1 = Wl[((dk * 4 + t) * 2 + 1) * 64 + l];
                acc[t] = __builtin_amdgcn_mfma_f32_16x16x32_bf16(b0, a0, acc[t], 0, 0, 0);
                acc[t] = __builtin_amdgcn_mfma_f32_16x16x32_bf16(b1, a1, acc[t], 0, 0, 0);
            }
            if (valid) {
                int iv = Is[(16 * w + cl) * KVOL + k];
                if (iv >= 0) {                 // single row: finalize now
                    float* dst = out + (size_t)iv * 64 + hi * 4;
                    #pragma unroll
                    for (int t = 0; t < 4; ++t) {
                        f32x4 y = acc[t] * scale4[t] + shift4[t];
                        #pragma unroll
                        for (int j = 0; j < 4; ++j) y[j] = y[j] > 0.f ? y[j] : 0.01f * y[j];
                        *reinterpret_cast<f32x4*>(dst + t * 16) = y;
                    }
                } else {                       // multi row: raw accumulate
                    int o = iv & 0x7fffffff;
                    float* dst = out + (size_t)o * 64 + hi * 4;
                    #pragma unroll
                    for (int t = 0; t < 4; ++t)
                        #pragma unroll
                        for (int j = 0; j < 4; ++j)
                            unsafeAtomicAdd(dst + t * 16 + j, acc[t][j]);
                }
            }
        }
    }
}

// BN+LeakyReLU in place for multi rows.
__global__ __launch_bounds__(256) void multi_apply(float* __restrict__ out,
                                                   const int* __restrict__ cnt,
                                                   const float* __restrict__ stats,
                                                   const float* __restrict__ gamma,
                                                   const float* __restrict__ beta,
                                                   int Nout) {
    const int tid = threadIdx.x;
    const int cg  = tid & 15;
    const int rs  = tid >> 4;
    const float inv = 1.0f / (float)Nout;
    f32x4 scale, shift;
    #pragma unroll
    for (int c = 0; c < 4; ++c) {
        float m   = stats[cg * 4 + c] * inv;
        float var = stats[64 + cg * 4 + c] * inv - m * m;
        float sc  = gamma[cg * 4 + c] * rsqrtf(var + 1e-5f);
        scale[c]  = sc;
        shift[c]  = beta[cg * 4 + c] - sc * m;
    }
    for (long r = (long)blockIdx.x * 16 + rs; r < Nout; r += (long)gridDim.x * 16) {
        if (cnt[r] > 1) {
            f32x4* p = reinterpret_cast<f32x4*>(out + (size_t)r * 64 + cg * 4);
            f32x4 v = *p;
            v = v * scale + shift;
            #pragma unroll
            for (int c = 0; c < 4; ++c) v[c] = v[c] > 0.f ? v[c] : 0.01f * v[c];
            *p = v;
        }
    }
}

// ---------------------------------------------------------------------------
// Fallback path (round-1 structure).
// ---------------------------------------------------------------------------
__global__ __launch_bounds__(256) void prep_fb(const float* __restrict__ W,
                                               unsigned short* __restrict__ wfrag) {
    int d = blockIdx.x * 256 + threadIdx.x;
    if (d < KVOL * 64 * 64) {
        int i    = d & 7;
        int lane = (d >> 3) & 63;
        int s    = (d >> 9) & 1;
        int t    = (d >> 10) & 3;
        int k    = d >> 12;
        int kin  = s * 32 + (lane >> 4) * 8 + i;
        int c    = t * 16 + (lane & 15);
        wfrag[d] = f2bf(W[k * 4096 + kin * 64 + c]);
    }
}

__global__ __launch_bounds__(256) void conv_scatter_fb(const float* __restrict__ feats,
                                                       const unsigned short* __restrict__ wfrag,
                                                       const int* __restrict__ oidx,
                                                       float* __restrict__ out,
                                                       int Npts) {
    __shared__ unsigned short As[64 * 64];
    __shared__ int Is[64 * KVOL];
    const int tid  = threadIdx.x;
    const int base = blockIdx.x * 64;
    stage_A(feats, As, base, Npts);
    for (int lin = tid; lin < 64 * KVOL; lin += 256) {
        int g = base * KVOL + lin;
        Is[lin] = (g < Npts * KVOL) ? oidx[g] : 0;
    }
    __syncthreads();
    const int w = tid >> 6, l = tid & 63, cl = l & 15, hi = l >> 4;
    const v8bf a0 = *reinterpret_cast<const v8bf*>(&As[(16 * w + cl) * 64 + hi * 8]);
    const v8bf a1 = *reinterpret_cast<const v8bf*>(&As[(16 * w + cl) * 64 + 32 + hi * 8]);
    const v8bf* wf = reinterpret_cast<const v8bf*>(wfrag);
    for (int k = 0; k < KVOL; ++k) {
        f32x4 acc[4];
        #pragma unroll
        for (int t = 0; t < 4; ++t) acc[t] = (f32x4){0.f, 0.f, 0.f, 0.f};
        #pragma unroll
        for (int t = 0; t < 4; ++t) {
            v8bf b0 = wf[((k * 4 + t) * 2 + 0) * 64 + l];
            v8bf b1 = wf[((k * 4 + t) * 2 + 1) * 64 + l];
            acc[t] = __builtin_amdgcn_mfma_f32_16x16x32_bf16(b0, a0, acc[t], 0, 0, 0);
            acc[t] = __builtin_amdgcn_mfma_f32_16x16x32_bf16(b1, a1, acc[t], 0, 0, 0);
        }
        if ((base + 16 * w + cl) < Npts) {
            int o = Is[(16 * w + cl) * KVOL + k];
            float* dst = out + (size_t)o * 64 + hi * 4;
            #pragma unroll
            for (int t = 0; t < 4; ++t)
                #pragma unroll
                for (int j = 0; j < 4; ++j)
                    unsafeAtomicAdd(dst + t * 16 + j, acc[t][j]);
        }
    }
}

__global__ __launch_bounds__(256) void bn_stats(const float* __restrict__ out,
                                                float* __restrict__ stats,
                                                int Nout) {
    const int tid = threadIdx.x;
    const int cg  = tid & 15;
    const int rs  = tid >> 4;
    f32x4 s = {0.f, 0.f, 0.f, 0.f}, q = {0.f, 0.f, 0.f, 0.f};
    for (long r = (long)blockIdx.x * 16 + rs; r < Nout; r += (long)gridDim.x * 16) {
        f32x4 v = *reinterpret_cast<const f32x4*>(out + (size_t)r * 64 + cg * 4);
        s += v;
        q += v * v;
    }
    __shared__ f32x4 sd[256];
    __shared__ f32x4 qd[256];
    sd[tid] = s; qd[tid] = q;
    __syncthreads();
    #pragma unroll
    for (int st = 8; st >= 1; st >>= 1) {
        if (rs < st) { sd[tid] += sd[tid + 16 * st]; qd[tid] += qd[tid + 16 * st]; }
        __syncthreads();
    }
    if (rs == 0) {
        #pragma unroll
        for (int c = 0; c < 4; ++c) {
            unsafeAtomicAdd(&stats[cg * 4 + c],      sd[tid][c]);
            unsafeAtomicAdd(&stats[64 + cg * 4 + c], qd[tid][c]);
        }
    }
}

__global__ __launch_bounds__(256) void bn_apply(float* __restrict__ out,
                                                const float* __restrict__ stats,
                                                const float* __restrict__ gamma,
                                                const float* __restrict__ beta,
                                                int Nout) {
    const int tid = threadIdx.x;
    const int cg  = tid & 15;
    const int rs  = tid >> 4;
    const float inv = 1.0f / (float)Nout;
    f32x4 scale, shift;
    #pragma unroll
    for (int c = 0; c < 4; ++c) {
        float m   = stats[cg * 4 + c] * inv;
        float var = stats[64 + cg * 4 + c] * inv - m * m;
        float sc  = gamma[cg * 4 + c] * rsqrtf(var + 1e-5f);
        scale[c]  = sc;
        shift[c]  = beta[cg * 4 + c] - sc * m;
    }
    for (long r = (long)blockIdx.x * 16 + rs; r < Nout; r += (long)gridDim.x * 16) {
        f32x4* p = reinterpret_cast<f32x4*>(out + (size_t)r * 64 + cg * 4);
        f32x4 v = *p;
        v = v * scale + shift;
        #pragma unroll
        for (int c = 0; c < 4; ++c) v[c] = v[c] > 0.f ? v[c] : 0.01f * v[c];
        *p = v;
    }
}

extern "C" void kernel_launch(void* const* d_in, const int* in_sizes, int n_in,
                              void* d_out, int out_size, void* d_ws, size_t ws_size,
                              hipStream_t stream) {
    const float* feats = (const float*)d_in[1];
    const float* W     = (const float*)d_in[2];
    const float* gamma = (const float*)d_in[3];
    const float* beta  = (const float*)d_in[4];
    const int*   oidx  = (const int*)d_in[5];
    float* out = (float*)d_out;

    const int Npts = in_sizes[1] / 64;   // 100000
    const int Nout = out_size / 64;      // ~2.51M
    const int M    = Npts * KVOL;

    // Workspace layout (~10.5 MB)
    char* ws = (char*)d_ws;
    float* stats  = (float*)ws;                            // 512 B
    float* colsum = (float*)(ws + 512);                    // 256 B
    float* S      = (float*)(ws + 4096);                   // 16 KiB
    unsigned short* wfrag = (unsigned short*)(ws + 32768); // 216 KiB
    int* cnt = (int*)(ws + 262144);                        // Nout*4
    const size_t ws_need = 262144 + (size_t)Nout * 4;

    const int cgrid = (Npts + 63) / 64;

    if (ws_size >= ws_need) {
        hipMemsetAsync(ws, 0, 32768, stream);              // stats + colsum + S
        hipMemsetAsync(cnt, 0, (size_t)Nout * sizeof(int), stream);
        hipLaunchKernelGGL(pre_all, dim3(NB_PREP + NB_CNT + NB_FS), dim3(256), 0, stream,
                           W, wfrag, oidx, cnt, feats, colsum, S, Npts);
        hipLaunchKernelGGL(mid_all, dim3(NB_Q + NB_ZM), dim3(256), 0, stream,
                           W, colsum, S, stats, out, cnt, Nout);
        hipLaunchKernelGGL(conv_fused, dim3(cgrid), dim3(256), 0, stream,
                           feats, wfrag, oidx, cnt, stats, gamma, beta, out, Npts, Nout);
        hipLaunchKernelGGL(multi_apply, dim3(2048), dim3(256), 0, stream,
                           out, cnt, stats, gamma, beta, Nout);
    } else {
        hipMemsetAsync(d_out, 0, (size_t)out_size * sizeof(float), stream);
        hipMemsetAsync(ws, 0, 512, stream);
        hipLaunchKernelGGL(prep_fb, dim3(432), dim3(256), 0, stream, W, wfrag);
        hipLaunchKernelGGL(conv_scatter_fb, dim3(cgrid), dim3(256), 0, stream,
                           feats, wfrag, oidx, out, Npts);
        hipLaunchKernelGGL(bn_stats, dim3(2048), dim3(256), 0, stream, out, stats, Nout);
        hipLaunchKernelGGL(bn_apply, dim3(2048), dim3(256), 0, stream, out, stats, gamma, beta, Nout);
    }
}

// Round 14
// 365.007 us; speedup vs baseline: 4.0910x; 1.0007x over previous
//
#include <hip/hip_runtime.h>
#include <hip/hip_bf16.h>

typedef __bf16 v8bf __attribute__((ext_vector_type(8)));
typedef float  f32x4 __attribute__((ext_vector_type(4)));

#define KVOL 27
#define KG   1      // taps staged to LDS per group (23.3KB LDS -> 6 blocks/CU)
#define NB_PREP 432
#define NB_CNT  2048
#define NB_FS   256
#define NB_Q    KVOL
#define NB_ZM   2048

__device__ __forceinline__ unsigned short f2bf(float f) {
    unsigned int u = __float_as_uint(f);
    u = u + 0x7FFFu + ((u >> 16) & 1u);   // round-to-nearest-even
    return (unsigned short)(u >> 16);
}
__device__ __forceinline__ float bf2f(unsigned short u) {
    return __uint_as_float((unsigned int)u << 16);
}

// ---------------------------------------------------------------------------
// pre_all: three independent jobs fused into one launch, selected by block id.
//   [0, NB_PREP)          : W -> bf16 MFMA fragments
//   [NB_PREP, +NB_CNT)    : count contributions per output row
//   [.., +NB_FS)          : feat_stats (colsum, S = feats^T feats via MFMA)
// ---------------------------------------------------------------------------
__global__ __launch_bounds__(256) void pre_all(const float* __restrict__ W,
                                               unsigned short* __restrict__ wfrag,
                                               const int* __restrict__ oidx,
                                               int* __restrict__ cnt,
                                               const float* __restrict__ feats,
                                               float* __restrict__ colsum,
                                               float* __restrict__ S,
                                               int Npts) {
    __shared__ unsigned short As[128 * 64];
    const int tid = threadIdx.x;
    const int bx  = blockIdx.x;
    const int M   = Npts * KVOL;

    if (bx < NB_PREP) {
        int d = bx * 256 + tid;
        if (d < KVOL * 64 * 64) {
            int i    = d & 7;
            int lane = (d >> 3) & 63;
            int s    = (d >> 9) & 1;
            int t    = (d >> 10) & 3;
            int k    = d >> 12;
            int kin  = s * 32 + (lane >> 4) * 8 + i;
            int c    = t * 16 + (lane & 15);
            wfrag[d] = f2bf(W[k * 4096 + kin * 64 + c]);
        }
        return;
    }
    if (bx < NB_PREP + NB_CNT) {
        int b = bx - NB_PREP;
        for (int e = b * 256 + tid; e < M; e += NB_CNT * 256)
            atomicAdd(&cnt[oidx[e]], 1);
        return;
    }
    // feat_stats
    {
        const int b = bx - (NB_PREP + NB_CNT);
        const int w = tid >> 6, l = tid & 63, cl = l & 15, hi = l >> 4;
        const int c = tid & 63, rg = tid >> 6;
        const __bf16* Ab = reinterpret_cast<const __bf16*>(As);

        f32x4 acc[4][4];
        #pragma unroll
        for (int a = 0; a < 4; ++a)
            #pragma unroll
            for (int bb = 0; bb < 4; ++bb) acc[a][bb] = (f32x4){0.f, 0.f, 0.f, 0.f};
        float csum = 0.f;

        for (int base = b * 128; base < Npts; base += NB_FS * 128) {
            __syncthreads();
            #pragma unroll
            for (int e = 0; e < 8; ++e) {
                int lin4 = e * 256 + tid;
                int row = lin4 >> 4, col = (lin4 & 15) * 4;
                float4 v = make_float4(0.f, 0.f, 0.f, 0.f);
                if (base + row < Npts)
                    v = *reinterpret_cast<const float4*>(feats + (size_t)(base + row) * 64 + col);
                int o = row * 64 + col;
                As[o + 0] = f2bf(v.x); As[o + 1] = f2bf(v.y);
                As[o + 2] = f2bf(v.z); As[o + 3] = f2bf(v.w);
            }
            __syncthreads();
            for (int r = 0; r < 32; ++r) csum += bf2f(As[(rg * 32 + r) * 64 + c]);
            v8bf f[4];
            #pragma unroll
            for (int t = 0; t < 4; ++t)
                #pragma unroll
                for (int i = 0; i < 8; ++i)
                    f[t][i] = Ab[(w * 32 + hi * 8 + i) * 64 + cl + 16 * t];
            #pragma unroll
            for (int a = 0; a < 4; ++a)
                #pragma unroll
                for (int bb = 0; bb < 4; ++bb)
                    acc[a][bb] = __builtin_amdgcn_mfma_f32_16x16x32_bf16(f[a], f[bb], acc[a][bb], 0, 0, 0);
        }

        unsafeAtomicAdd(&colsum[c], csum);
        #pragma unroll
        for (int a = 0; a < 4; ++a)
            #pragma unroll
            for (int bb = 0; bb < 4; ++bb)
                #pragma unroll
                for (int r = 0; r < 4; ++r) {
                    int i = a * 16 + hi * 4 + r;
                    int j = bb * 16 + cl;
                    unsafeAtomicAdd(&S[i * 64 + j], acc[a][bb][r]);
                }
    }
}

// ---------------------------------------------------------------------------
// mid_all: two independent jobs fused:
//   [0, NB_Q)   : qall_mean — stats[c] += colsum.w ; stats[64+c] += w^T S w
//   [NB_Q, ..)  : zero_multi — zero rows with cnt >= 2
// ---------------------------------------------------------------------------
__global__ __launch_bounds__(256) void mid_all(const float* __restrict__ W,
                                               const float* __restrict__ colsum,
                                               const float* __restrict__ S,
                                               float* __restrict__ stats,
                                               float* __restrict__ out,
                                               const int* __restrict__ cnt,
                                               int Nout) {
    __shared__ float Sl[4096];
    __shared__ float Wl[4096];
    __shared__ float cs[64];
    const int tid = threadIdx.x;
    const int bx  = blockIdx.x;

    if (bx < NB_Q) {
        const int k = bx;
        for (int lin = tid; lin < 4096; lin += 256) {
            Sl[lin] = S[lin];
            Wl[lin] = W[k * 4096 + lin];
        }
        if (tid < 64) cs[tid] = colsum[tid];
        __syncthreads();
        if (tid < 64) {
            const int c = tid;
            float q = 0.f, sm = 0.f;
            for (int i = 0; i < 64; ++i) {
                float wi = Wl[i * 64 + c];
                sm += cs[i] * wi;
                float d = 0.f;
                #pragma unroll 8
                for (int j = 0; j < 64; ++j) d += Sl[i * 64 + j] * Wl[j * 64 + c];
                q += wi * d;
            }
            unsafeAtomicAdd(&stats[64 + c], q);
            unsafeAtomicAdd(&stats[c], sm);
        }
        return;
    }
    // zero_multi
    {
        const int b = bx - NB_Q;
        const int sub = tid & 3;
        const long step = (long)NB_ZM * 64;
        for (long r = (long)b * 64 + (tid >> 2); r < Nout; r += step) {
            if (cnt[r] > 1) {
                f32x4 z = {0.f, 0.f, 0.f, 0.f};
                f32x4* p = reinterpret_cast<f32x4*>(out + r * 64) + sub;
                p[0] = z; p[4] = z; p[8] = z; p[12] = z;
            }
        }
    }
}

// Stage bf16 A tile from fp32 feats (natural order).
__device__ __forceinline__ void stage_A(const float* __restrict__ feats,
                                        unsigned short* As, int base, int Npts) {
    const int tid = threadIdx.x;
    #pragma unroll
    for (int e = 0; e < 4; ++e) {
        int lin = e * 1024 + tid * 4;
        int row = lin >> 6, col = lin & 63;
        float4 v = make_float4(0.f, 0.f, 0.f, 0.f);
        if (base + row < Npts)
            v = *reinterpret_cast<const float4*>(feats + (size_t)(base + row) * 64 + col);
        As[lin + 0] = f2bf(v.x);
        As[lin + 1] = f2bf(v.y);
        As[lin + 2] = f2bf(v.z);
        As[lin + 3] = f2bf(v.w);
    }
}

// ---------------------------------------------------------------------------
// THE single conv pass. Swapped-operand MFMA: lane (hi,cl) holds channels
// t*16+hi*4+{0..3} of point-row cl. W LDS-staged in KG-tap groups.
// Single rows: BN+LeakyReLU in-register -> plain dwordx4 store.
// Multi rows: raw (pre-BN) atomicAdd; BN'd later by multi_apply.
// ---------------------------------------------------------------------------
__global__ __launch_bounds__(256) void conv_fused(const float* __restrict__ feats,
                                                  const unsigned short* __restrict__ wfrag,
                                                  const int* __restrict__ oidx,
                                                  const int* __restrict__ cnt,
                                                  const float* __restrict__ stats,
                                                  const float* __restrict__ gamma,
                                                  const float* __restrict__ beta,
                                                  float* __restrict__ out,
                                                  int Npts, int Nout) {
    __shared__ unsigned short As[64 * 64];
    __shared__ int Is[64 * KVOL];
    __shared__ unsigned short Ws[KG * 4096];

    const int tid  = threadIdx.x;
    const int base = blockIdx.x * 64;
    const int M    = Npts * KVOL;

    stage_A(feats, As, base, Npts);
    for (int lin = tid; lin < 64 * KVOL; lin += 256) {
        int g = base * KVOL + lin;
        int iv = 0;
        if (g < M) {
            int o = oidx[g];
            iv = o | (cnt[o] > 1 ? 0x80000000 : 0);
        }
        Is[lin] = iv;
    }
    __syncthreads();

    const int w = tid >> 6, l = tid & 63, cl = l & 15, hi = l >> 4;
    const bool valid = (base + 16 * w + cl) < Npts;
    const v8bf a0 = *reinterpret_cast<const v8bf*>(&As[(16 * w + cl) * 64 + hi * 8]);
    const v8bf a1 = *reinterpret_cast<const v8bf*>(&As[(16 * w + cl) * 64 + 32 + hi * 8]);
    const v8bf* wfv = reinterpret_cast<const v8bf*>(wfrag);
    v8bf*       Wv  = reinterpret_cast<v8bf*>(Ws);
    const v8bf* Wl  = reinterpret_cast<const v8bf*>(Ws);

    const float inv = 1.0f / (float)Nout;
    f32x4 scale4[4], shift4[4];
    #pragma unroll
    for (int t = 0; t < 4; ++t) {
        int c0 = t * 16 + hi * 4;
        f32x4 m4 = *reinterpret_cast<const f32x4*>(stats + c0);
        f32x4 v4 = *reinterpret_cast<const f32x4*>(stats + 64 + c0);
        f32x4 g4 = *reinterpret_cast<const f32x4*>(gamma + c0);
        f32x4 b4 = *reinterpret_cast<const f32x4*>(beta + c0);
        #pragma unroll
        for (int j = 0; j < 4; ++j) {
            float m   = m4[j] * inv;
            float var = v4[j] * inv - m * m;
            float sc  = g4[j] * rsqrtf(var + 1e-5f);
            scale4[t][j] = sc;
            shift4[t][j] = b4[j] - sc * m;
        }
    }

    for (int k0 = 0; k0 < KVOL; k0 += KG) {
        const int kn = (KVOL - k0) < KG ? (KVOL - k0) : KG;
        __syncthreads();
        for (int j = tid; j < kn * 512; j += 256)
            Wv[j] = wfv[k0 * 512 + j];
        __syncthreads();

        for (int dk = 0; dk < kn; ++dk) {
            const int k = k0 + dk;
            f32x4 acc[4];
            #pragma unroll
            for (int t = 0; t < 4; ++t) acc[t] = (f32x4){0.f, 0.f, 0.f, 0.f};
            #pragma unroll
            for (int t = 0; t < 4; ++t) {
                v8bf b0 = Wl[((dk * 4 + t) * 2 + 0) * 64 + l];
                v8bf b1 = Wl[((dk * 4 + t) * 2 + 1) * 64 + l];
                acc[t] = __builtin_amdgcn_mfma_f32_16x16x32_bf16(b0, a0, acc[t], 0, 0, 0);
                acc[t] = __builtin_amdgcn_mfma_f32_16x16x32_bf16(b1, a1, acc[t], 0, 0, 0);
            }
            if (valid) {
                int iv = Is[(16 * w + cl) * KVOL + k];
                if (iv >= 0) {                 // single row: finalize now
                    float* dst = out + (size_t)iv * 64 + hi * 4;
                    #pragma unroll
                    for (int t = 0; t < 4; ++t) {
                        f32x4 y = acc[t] * scale4[t] + shift4[t];
                        #pragma unroll
                        for (int j = 0; j < 4; ++j) y[j] = y[j] > 0.f ? y[j] : 0.01f * y[j];
                        *reinterpret_cast<f32x4*>(dst + t * 16) = y;
                    }
                } else {                       // multi row: raw accumulate
                    int o = iv & 0x7fffffff;
                    float* dst = out + (size_t)o * 64 + hi * 4;
                    #pragma unroll
                    for (int t = 0; t < 4; ++t)
                        #pragma unroll
                        for (int j = 0; j < 4; ++j)
                            unsafeAtomicAdd(dst + t * 16 + j, acc[t][j]);
                }
            }
        }
    }
}

// BN+LeakyReLU in place for multi rows.
__global__ __launch_bounds__(256) void multi_apply(float* __restrict__ out,
                                                   const int* __restrict__ cnt,
                                                   const float* __restrict__ stats,
                                                   const float* __restrict__ gamma,
                                                   const float* __restrict__ beta,
                                                   int Nout) {
    const int tid = threadIdx.x;
    const int cg  = tid & 15;
    const int rs  = tid >> 4;
    const float inv = 1.0f / (float)Nout;
    f32x4 scale, shift;
    #pragma unroll
    for (int c = 0; c < 4; ++c) {
        float m   = stats[cg * 4 + c] * inv;
        float var = stats[64 + cg * 4 + c] * inv - m * m;
        float sc  = gamma[cg * 4 + c] * rsqrtf(var + 1e-5f);
        scale[c]  = sc;
        shift[c]  = beta[cg * 4 + c] - sc * m;
    }
    for (long r = (long)blockIdx.x * 16 + rs; r < Nout; r += (long)gridDim.x * 16) {
        if (cnt[r] > 1) {
            f32x4* p = reinterpret_cast<f32x4*>(out + (size_t)r * 64 + cg * 4);
            f32x4 v = *p;
            v = v * scale + shift;
            #pragma unroll
            for (int c = 0; c < 4; ++c) v[c] = v[c] > 0.f ? v[c] : 0.01f * v[c];
            *p = v;
        }
    }
}

// ---------------------------------------------------------------------------
// Fallback path (round-1 structure).
// ---------------------------------------------------------------------------
__global__ __launch_bounds__(256) void prep_fb(const float* __restrict__ W,
                                               unsigned short* __restrict__ wfrag) {
    int d = blockIdx.x * 256 + threadIdx.x;
    if (d < KVOL * 64 * 64) {
        int i    = d & 7;
        int lane = (d >> 3) & 63;
        int s    = (d >> 9) & 1;
        int t    = (d >> 10) & 3;
        int k    = d >> 12;
        int kin  = s * 32 + (lane >> 4) * 8 + i;
        int c    = t * 16 + (lane & 15);
        wfrag[d] = f2bf(W[k * 4096 + kin * 64 + c]);
    }
}

__global__ __launch_bounds__(256) void conv_scatter_fb(const float* __restrict__ feats,
                                                       const unsigned short* __restrict__ wfrag,
                                                       const int* __restrict__ oidx,
                                                       float* __restrict__ out,
                                                       int Npts) {
    __shared__ unsigned short As[64 * 64];
    __shared__ int Is[64 * KVOL];
    const int tid  = threadIdx.x;
    const int base = blockIdx.x * 64;
    stage_A(feats, As, base, Npts);
    for (int lin = tid; lin < 64 * KVOL; lin += 256) {
        int g = base * KVOL + lin;
        Is[lin] = (g < Npts * KVOL) ? oidx[g] : 0;
    }
    __syncthreads();
    const int w = tid >> 6, l = tid & 63, cl = l & 15, hi = l >> 4;
    const v8bf a0 = *reinterpret_cast<const v8bf*>(&As[(16 * w + cl) * 64 + hi * 8]);
    const v8bf a1 = *reinterpret_cast<const v8bf*>(&As[(16 * w + cl) * 64 + 32 + hi * 8]);
    const v8bf* wf = reinterpret_cast<const v8bf*>(wfrag);
    for (int k = 0; k < KVOL; ++k) {
        f32x4 acc[4];
        #pragma unroll
        for (int t = 0; t < 4; ++t) acc[t] = (f32x4){0.f, 0.f, 0.f, 0.f};
        #pragma unroll
        for (int t = 0; t < 4; ++t) {
            v8bf b0 = wf[((k * 4 + t) * 2 + 0) * 64 + l];
            v8bf b1 = wf[((k * 4 + t) * 2 + 1) * 64 + l];
            acc[t] = __builtin_amdgcn_mfma_f32_16x16x32_bf16(b0, a0, acc[t], 0, 0, 0);
            acc[t] = __builtin_amdgcn_mfma_f32_16x16x32_bf16(b1, a1, acc[t], 0, 0, 0);
        }
        if ((base + 16 * w + cl) < Npts) {
            int o = Is[(16 * w + cl) * KVOL + k];
            float* dst = out + (size_t)o * 64 + hi * 4;
            #pragma unroll
            for (int t = 0; t < 4; ++t)
                #pragma unroll
                for (int j = 0; j < 4; ++j)
                    unsafeAtomicAdd(dst + t * 16 + j, acc[t][j]);
        }
    }
}

__global__ __launch_bounds__(256) void bn_stats(const float* __restrict__ out,
                                                float* __restrict__ stats,
                                                int Nout) {
    const int tid = threadIdx.x;
    const int cg  = tid & 15;
    const int rs  = tid >> 4;
    f32x4 s = {0.f, 0.f, 0.f, 0.f}, q = {0.f, 0.f, 0.f, 0.f};
    for (long r = (long)blockIdx.x * 16 + rs; r < Nout; r += (long)gridDim.x * 16) {
        f32x4 v = *reinterpret_cast<const f32x4*>(out + (size_t)r * 64 + cg * 4);
        s += v;
        q += v * v;
    }
    __shared__ f32x4 sd[256];
    __shared__ f32x4 qd[256];
    sd[tid] = s; qd[tid] = q;
    __syncthreads();
    #pragma unroll
    for (int st = 8; st >= 1; st >>= 1) {
        if (rs < st) { sd[tid] += sd[tid + 16 * st]; qd[tid] += qd[tid + 16 * st]; }
        __syncthreads();
    }
    if (rs == 0) {
        #pragma unroll
        for (int c = 0; c < 4; ++c) {
            unsafeAtomicAdd(&stats[cg * 4 + c],      sd[tid][c]);
            unsafeAtomicAdd(&stats[64 + cg * 4 + c], qd[tid][c]);
        }
    }
}

__global__ __launch_bounds__(256) void bn_apply(float* __restrict__ out,
                                                const float* __restrict__ stats,
                                                const float* __restrict__ gamma,
                                                const float* __restrict__ beta,
                                                int Nout) {
    const int tid = threadIdx.x;
    const int cg  = tid & 15;
    const int rs  = tid >> 4;
    const float inv = 1.0f / (float)Nout;
    f32x4 scale, shift;
    #pragma unroll
    for (int c = 0; c < 4; ++c) {
        float m   = stats[cg * 4 + c] * inv;
        float var = stats[64 + cg * 4 + c] * inv - m * m;
        float sc  = gamma[cg * 4 + c] * rsqrtf(var + 1e-5f);
        scale[c]  = sc;
        shift[c]  = beta[cg * 4 + c] - sc * m;
    }
    for (long r = (long)blockIdx.x * 16 + rs; r < Nout; r += (long)gridDim.x * 16) {
        f32x4* p = reinterpret_cast<f32x4*>(out + (size_t)r * 64 + cg * 4);
        f32x4 v = *p;
        v = v * scale + shift;
        #pragma unroll
        for (int c = 0; c < 4; ++c) v[c] = v[c] > 0.f ? v[c] : 0.01f * v[c];
        *p = v;
    }
}

extern "C" void kernel_launch(void* const* d_in, const int* in_sizes, int n_in,
                              void* d_out, int out_size, void* d_ws, size_t ws_size,
                              hipStream_t stream) {
    const float* feats = (const float*)d_in[1];
    const float* W     = (const float*)d_in[2];
    const float* gamma = (const float*)d_in[3];
    const float* beta  = (const float*)d_in[4];
    const int*   oidx  = (const int*)d_in[5];
    float* out = (float*)d_out;

    const int Npts = in_sizes[1] / 64;   // 100000
    const int Nout = out_size / 64;      // ~2.51M
    const int M    = Npts * KVOL;

    // Workspace layout (~10.5 MB)
    char* ws = (char*)d_ws;
    float* stats  = (float*)ws;                            // 512 B
    float* colsum = (float*)(ws + 512);                    // 256 B
    float* S      = (float*)(ws + 4096);                   // 16 KiB
    unsigned short* wfrag = (unsigned short*)(ws + 32768); // 216 KiB
    int* cnt = (int*)(ws + 262144);                        // Nout*4
    const size_t ws_need = 262144 + (size_t)Nout * 4;

    const int cgrid = (Npts + 63) / 64;

    if (ws_size >= ws_need) {
        hipMemsetAsync(ws, 0, 32768, stream);              // stats + colsum + S
        hipMemsetAsync(cnt, 0, (size_t)Nout * sizeof(int), stream);
        hipLaunchKernelGGL(pre_all, dim3(NB_PREP + NB_CNT + NB_FS), dim3(256), 0, stream,
                           W, wfrag, oidx, cnt, feats, colsum, S, Npts);
        hipLaunchKernelGGL(mid_all, dim3(NB_Q + NB_ZM), dim3(256), 0, stream,
                           W, colsum, S, stats, out, cnt, Nout);
        hipLaunchKernelGGL(conv_fused, dim3(cgrid), dim3(256), 0, stream,
                           feats, wfrag, oidx, cnt, stats, gamma, beta, out, Npts, Nout);
        hipLaunchKernelGGL(multi_apply, dim3(2048), dim3(256), 0, stream,
                           out, cnt, stats, gamma, beta, Nout);
    } else {
        hipMemsetAsync(d_out, 0, (size_t)out_size * sizeof(float), stream);
        hipMemsetAsync(ws, 0, 512, stream);
        hipLaunchKernelGGL(prep_fb, dim3(432), dim3(256), 0, stream, W, wfrag);
        hipLaunchKernelGGL(conv_scatter_fb, dim3(cgrid), dim3(256), 0, stream,
                           feats, wfrag, oidx, out, Npts);
        hipLaunchKernelGGL(bn_stats, dim3(2048), dim3(256), 0, stream, out, stats, Nout);
        hipLaunchKernelGGL(bn_apply, dim3(2048), dim3(256), 0, stream, out, stats, gamma, beta, Nout);
    }
}